// Round 1
// baseline (390.024 us; speedup 1.0000x reference)
//
#include <hip/hip_runtime.h>

#define NSH 512    // NUM_SHARDS
#define NC  256    // NUM_CLUSTERS
#define NI  1024   // INPUT_SIZE
#define NO  1024   // OUTPUT_SIZE
#define NB  1024   // BATCH
#define NMAX 8     // samples processed per pass per shard-block

// ---------------- Kernel 1: group samples by shard (counting sort) ----------
__global__ __launch_bounds__(512) void group_kernel(const int* __restrict__ shard,
                                                    int* __restrict__ order,
                                                    int* __restrict__ base,
                                                    int* __restrict__ cnt) {
    __shared__ int h[NSH];
    __shared__ int b0[NSH];
    __shared__ int cur[NSH];
    const int tid = threadIdx.x;   // 512 threads == NSH
    h[tid] = 0;
    __syncthreads();
    for (int i = tid; i < NB; i += 512) atomicAdd(&h[shard[i]], 1);
    __syncthreads();
    if (tid == 0) {
        int acc = 0;
        for (int s = 0; s < NSH; ++s) { b0[s] = acc; acc += h[s]; }
    }
    __syncthreads();
    cnt[tid]  = h[tid];
    base[tid] = b0[tid];
    cur[tid]  = b0[tid];
    __syncthreads();
    for (int i = tid; i < NB; i += 512) {
        int pos = atomicAdd(&cur[shard[i]], 1);
        order[pos] = i;
    }
}

// ---------------- Kernel 2: per-shard fused gather+vecmat+softmax+combine ---
__global__ __launch_bounds__(256) void slb_kernel(
        const int*   __restrict__ order,
        const int*   __restrict__ base,
        const int*   __restrict__ cnt,
        const float* __restrict__ key,
        const float* __restrict__ lat,
        const float* __restrict__ wgt,
        const float* __restrict__ bias,
        float*       __restrict__ out) {
    const int s     = blockIdx.x;
    const int n_tot = cnt[s];
    if (n_tot == 0) return;
    const int b0   = base[s];
    const int tid  = threadIdx.x;          // 0..255
    const int wave = tid >> 6;             // 0..3
    const int lane = tid & 63;
    const int isub = wave;                 // i-phase for phase 1
    const int c4   = (tid & 63) << 2;      // cluster base for phase 1 float4

    const float* __restrict__ W = wgt + (size_t)s * (NI * NC);
    const float* __restrict__ L = lat + (size_t)s * (NC * NO);
    const float  bsc = bias[s * NC + tid]; // bias for cluster c = tid

    __shared__ float key_s[NMAX][NI];      // 32 KB
    __shared__ float prob_s[NMAX][NC];     //  8 KB
    __shared__ float red_s[4][NC];         //  4 KB
    __shared__ float xw[4];
    __shared__ int   samp_s[NMAX];

    float* __restrict__ outp = out;                       // lat_h [NB][NO]
    float* __restrict__ outq = out + (size_t)NB * NO;     // prob  [NB][NC]

    for (int p0 = 0; p0 < n_tot; p0 += NMAX) {
        const int n = min(NMAX, n_tot - p0);
        __syncthreads();                      // protect samp_s/prob_s reuse
        if (tid < n) samp_s[tid] = order[b0 + p0 + tid];
        __syncthreads();

        // ---- stage keys into LDS (zero-pad unused rows) ----
        for (int idx = tid; idx < NMAX * (NI / 4); idx += 256) {
            const int ns = idx >> 8;          // sample slot
            const int e4 = idx & 255;         // float4 index within row
            float4 v = make_float4(0.f, 0.f, 0.f, 0.f);
            if (ns < n)
                v = *(const float4*)(key + (size_t)samp_s[ns] * NI + (e4 << 2));
            *(float4*)&key_s[ns][e4 << 2] = v;
        }
        __syncthreads();

        // ---- phase 1: logit[c] = sum_i key[i] * W[i][c]  (stream W once) ----
        float4 acc[NMAX];
        #pragma unroll
        for (int j = 0; j < NMAX; ++j) acc[j] = make_float4(0.f, 0.f, 0.f, 0.f);

        for (int i = isub; i < NI; i += 4) {
            const float4 wv = *(const float4*)(W + (size_t)i * NC + c4);
            #pragma unroll
            for (int j = 0; j < NMAX; ++j) {
                const float k = key_s[j][i];   // LDS broadcast (i uniform per wave)
                acc[j].x = fmaf(k, wv.x, acc[j].x);
                acc[j].y = fmaf(k, wv.y, acc[j].y);
                acc[j].z = fmaf(k, wv.z, acc[j].z);
                acc[j].w = fmaf(k, wv.w, acc[j].w);
            }
        }

        // ---- reduce partials across the 4 i-phases + softmax, per sample ----
        #pragma unroll
        for (int j = 0; j < NMAX; ++j) {
            __syncthreads();                          // red_s free
            *(float4*)&red_s[isub][c4] = acc[j];
            __syncthreads();
            float lg = red_s[0][tid] + red_s[1][tid] + red_s[2][tid]
                     + red_s[3][tid] + bsc;
            // block-wide softmax over 256 values (4 waves)
            float m = lg;
            #pragma unroll
            for (int off = 32; off >= 1; off >>= 1)
                m = fmaxf(m, __shfl_xor(m, off, 64));
            if (lane == 0) xw[wave] = m;
            __syncthreads();
            m = fmaxf(fmaxf(xw[0], xw[1]), fmaxf(xw[2], xw[3]));
            const float e = __expf(lg - m);
            float sm = e;
            #pragma unroll
            for (int off = 32; off >= 1; off >>= 1)
                sm += __shfl_xor(sm, off, 64);
            __syncthreads();                          // xw reuse
            if (lane == 0) xw[wave] = sm;
            __syncthreads();
            sm = xw[0] + xw[1] + xw[2] + xw[3];
            const float p = e / sm;
            prob_s[j][tid] = p;                       // finite even for j >= n
            if (j < n) outq[(size_t)samp_s[j] * NC + tid] = p;
        }
        __syncthreads();

        // ---- phase 2: lat_h[o] = sum_c prob[c] * L[c][o]  (stream L once) ----
        float4 oacc[NMAX];
        #pragma unroll
        for (int j = 0; j < NMAX; ++j) oacc[j] = make_float4(0.f, 0.f, 0.f, 0.f);

        const int o4 = tid << 2;
        for (int c = 0; c < NC; ++c) {
            const float4 lv = *(const float4*)(L + (size_t)c * NO + o4);
            #pragma unroll
            for (int j = 0; j < NMAX; ++j) {
                const float p = prob_s[j][c];          // LDS broadcast
                oacc[j].x = fmaf(p, lv.x, oacc[j].x);
                oacc[j].y = fmaf(p, lv.y, oacc[j].y);
                oacc[j].z = fmaf(p, lv.z, oacc[j].z);
                oacc[j].w = fmaf(p, lv.w, oacc[j].w);
            }
        }
        #pragma unroll
        for (int j = 0; j < NMAX; ++j) {
            if (j < n)
                *(float4*)(outp + (size_t)samp_s[j] * NO + o4) = oacc[j];
        }
    }
}

// ---------------- launch ----------------------------------------------------
extern "C" void kernel_launch(void* const* d_in, const int* in_sizes, int n_in,
                              void* d_out, int out_size, void* d_ws, size_t ws_size,
                              hipStream_t stream) {
    const int*   shard = (const int*)  d_in[0];
    const float* key   = (const float*)d_in[1];
    const float* lat   = (const float*)d_in[2];
    const float* wgt   = (const float*)d_in[3];
    const float* bias  = (const float*)d_in[4];
    float* out = (float*)d_out;

    int* order = (int*)d_ws;          // [NB]
    int* base  = order + NB;          // [NSH]
    int* cnt   = base + NSH;          // [NSH]

    group_kernel<<<1, 512, 0, stream>>>(shard, order, base, cnt);
    slb_kernel<<<NSH, 256, 0, stream>>>(order, base, cnt, key, lat, wgt, bias, out);
}

// Round 2
// 305.859 us; speedup vs baseline: 1.2752x; 1.2752x over previous
//
#include <hip/hip_runtime.h>

#define NSH 512    // NUM_SHARDS
#define NC  256    // NUM_CLUSTERS
#define NI  1024   // INPUT_SIZE
#define NO  1024   // OUTPUT_SIZE
#define NB  1024   // BATCH
#define NMAX 8     // samples processed per pass per shard-block
#define UF  8      // load-pipeline depth (float4 loads in flight)

// ---------------- Kernel 1: group samples by shard (counting sort) ----------
__global__ __launch_bounds__(512) void group_kernel(const int* __restrict__ shard,
                                                    int* __restrict__ order,
                                                    int* __restrict__ base,
                                                    int* __restrict__ cnt) {
    __shared__ int h[NSH];
    __shared__ int b0[NSH];
    __shared__ int cur[NSH];
    const int tid = threadIdx.x;   // 512 threads == NSH
    h[tid] = 0;
    __syncthreads();
    for (int i = tid; i < NB; i += 512) atomicAdd(&h[shard[i]], 1);
    __syncthreads();
    if (tid == 0) {
        int acc = 0;
        for (int s = 0; s < NSH; ++s) { b0[s] = acc; acc += h[s]; }
    }
    __syncthreads();
    cnt[tid]  = h[tid];
    base[tid] = b0[tid];
    cur[tid]  = b0[tid];
    __syncthreads();
    for (int i = tid; i < NB; i += 512) {
        int pos = atomicAdd(&cur[shard[i]], 1);
        order[pos] = i;
    }
}

// ---------------- Kernel 2: per-shard fused gather+vecmat+softmax+combine ---
__global__ __launch_bounds__(256, 3) void slb_kernel(
        const int*   __restrict__ order,
        const int*   __restrict__ base,
        const int*   __restrict__ cnt,
        const float* __restrict__ key,
        const float* __restrict__ lat,
        const float* __restrict__ wgt,
        const float* __restrict__ bias,
        float*       __restrict__ out) {
    const int s     = blockIdx.x;
    const int n_tot = cnt[s];
    if (n_tot == 0) return;
    const int b0   = base[s];
    const int tid  = threadIdx.x;          // 0..255
    const int wave = tid >> 6;             // 0..3
    const int lane = tid & 63;
    const int isub = wave;                 // i-phase for phase 1
    const int c4   = (tid & 63) << 2;      // cluster base for phase 1 float4

    const float* __restrict__ W = wgt + (size_t)s * (NI * NC);
    const float* __restrict__ L = lat + (size_t)s * (NC * NO);
    const float  bsc = bias[s * NC + tid]; // bias for cluster c = tid

    __shared__ float key_s[NMAX][NI];      // 32 KB
    __shared__ float prob_s[NMAX][NC];     //  8 KB
    __shared__ float red_s[4][NC];         //  4 KB
    __shared__ float xw[4];
    __shared__ int   samp_s[NMAX];

    float* __restrict__ outp = out;                       // lat_h [NB][NO]
    float* __restrict__ outq = out + (size_t)NB * NO;     // prob  [NB][NC]

    for (int p0 = 0; p0 < n_tot; p0 += NMAX) {
        const int n = min(NMAX, n_tot - p0);
        __syncthreads();                      // protect samp_s/prob_s reuse
        if (tid < n) samp_s[tid] = order[b0 + p0 + tid];
        __syncthreads();

        // ---- stage keys into LDS (zero-pad unused rows) ----
        for (int idx = tid; idx < NMAX * (NI / 4); idx += 256) {
            const int ns = idx >> 8;          // sample slot
            const int e4 = idx & 255;         // float4 index within row
            float4 v = make_float4(0.f, 0.f, 0.f, 0.f);
            if (ns < n)
                v = *(const float4*)(key + (size_t)samp_s[ns] * NI + (e4 << 2));
            *(float4*)&key_s[ns][e4 << 2] = v;
        }
        __syncthreads();

        // ---- phase 1: logit[c] = sum_i key[i] * W[i][c]  (stream W once) ----
        // Pipelined: UF independent float4 loads issued back-to-back, then FMAs.
        float4 acc[NMAX];
        #pragma unroll
        for (int j = 0; j < NMAX; ++j) acc[j] = make_float4(0.f, 0.f, 0.f, 0.f);

        for (int i0 = isub; i0 < NI; i0 += 4 * UF) {
            float4 wv[UF];
            #pragma unroll
            for (int u = 0; u < UF; ++u)
                wv[u] = *(const float4*)(W + (size_t)(i0 + 4 * u) * NC + c4);
            #pragma unroll
            for (int u = 0; u < UF; ++u) {
                const int i = i0 + 4 * u;
                #pragma unroll
                for (int j = 0; j < NMAX; ++j) {
                    const float k = key_s[j][i];   // LDS broadcast
                    acc[j].x = fmaf(k, wv[u].x, acc[j].x);
                    acc[j].y = fmaf(k, wv[u].y, acc[j].y);
                    acc[j].z = fmaf(k, wv[u].z, acc[j].z);
                    acc[j].w = fmaf(k, wv[u].w, acc[j].w);
                }
            }
        }

        // ---- reduce partials across the 4 i-phases + softmax, per sample ----
        #pragma unroll
        for (int j = 0; j < NMAX; ++j) {
            __syncthreads();                          // red_s free
            *(float4*)&red_s[isub][c4] = acc[j];
            __syncthreads();
            float lg = red_s[0][tid] + red_s[1][tid] + red_s[2][tid]
                     + red_s[3][tid] + bsc;
            // block-wide softmax over 256 values (4 waves)
            float m = lg;
            #pragma unroll
            for (int off = 32; off >= 1; off >>= 1)
                m = fmaxf(m, __shfl_xor(m, off, 64));
            if (lane == 0) xw[wave] = m;
            __syncthreads();
            m = fmaxf(fmaxf(xw[0], xw[1]), fmaxf(xw[2], xw[3]));
            const float e = __expf(lg - m);
            float sm = e;
            #pragma unroll
            for (int off = 32; off >= 1; off >>= 1)
                sm += __shfl_xor(sm, off, 64);
            __syncthreads();                          // xw reuse
            if (lane == 0) xw[wave] = sm;
            __syncthreads();
            sm = xw[0] + xw[1] + xw[2] + xw[3];
            const float p = e / sm;
            prob_s[j][tid] = p;                       // finite even for j >= n
            if (j < n) outq[(size_t)samp_s[j] * NC + tid] = p;
        }
        __syncthreads();

        // ---- phase 2: lat_h[o] = sum_c prob[c] * L[c][o]  (stream L once) ----
        float4 oacc[NMAX];
        #pragma unroll
        for (int j = 0; j < NMAX; ++j) oacc[j] = make_float4(0.f, 0.f, 0.f, 0.f);

        const int o4 = tid << 2;
        for (int c0 = 0; c0 < NC; c0 += UF) {
            float4 lv[UF];
            #pragma unroll
            for (int u = 0; u < UF; ++u)
                lv[u] = *(const float4*)(L + (size_t)(c0 + u) * NO + o4);
            #pragma unroll
            for (int u = 0; u < UF; ++u) {
                #pragma unroll
                for (int j = 0; j < NMAX; ++j) {
                    const float p = prob_s[j][c0 + u]; // LDS broadcast
                    oacc[j].x = fmaf(p, lv[u].x, oacc[j].x);
                    oacc[j].y = fmaf(p, lv[u].y, oacc[j].y);
                    oacc[j].z = fmaf(p, lv[u].z, oacc[j].z);
                    oacc[j].w = fmaf(p, lv[u].w, oacc[j].w);
                }
            }
        }
        #pragma unroll
        for (int j = 0; j < NMAX; ++j) {
            if (j < n)
                *(float4*)(outp + (size_t)samp_s[j] * NO + o4) = oacc[j];
        }
    }
}

// ---------------- launch ----------------------------------------------------
extern "C" void kernel_launch(void* const* d_in, const int* in_sizes, int n_in,
                              void* d_out, int out_size, void* d_ws, size_t ws_size,
                              hipStream_t stream) {
    const int*   shard = (const int*)  d_in[0];
    const float* key   = (const float*)d_in[1];
    const float* lat   = (const float*)d_in[2];
    const float* wgt   = (const float*)d_in[3];
    const float* bias  = (const float*)d_in[4];
    float* out = (float*)d_out;

    int* order = (int*)d_ws;          // [NB]
    int* base  = order + NB;          // [NSH]
    int* cnt   = base + NSH;          // [NSH]

    group_kernel<<<1, 512, 0, stream>>>(shard, order, base, cnt);
    slb_kernel<<<NSH, 256, 0, stream>>>(order, base, cnt, key, lat, wgt, bias, out);
}

// Round 3
// 195.151 us; speedup vs baseline: 1.9986x; 1.5673x over previous
//
#include <hip/hip_runtime.h>

#define NSH 512    // NUM_SHARDS
#define NC  256    // NUM_CLUSTERS
#define NI  1024   // INPUT_SIZE
#define NO  1024   // OUTPUT_SIZE
#define NB  1024   // BATCH
#define NMAX 8     // samples per pass per shard-block
#define IC  4      // i-chunks for logit kernel
#define OC  4      // o-chunks for combine kernel
#define UF  4      // float4 loads in flight per thread

// ---------------- Kernel 1: group samples by shard (counting sort) ----------
__global__ __launch_bounds__(512) void group_kernel(const int* __restrict__ shard,
                                                    int* __restrict__ order,
                                                    int* __restrict__ base,
                                                    int* __restrict__ cnt) {
    __shared__ int h[NSH];
    __shared__ int b0[NSH];
    __shared__ int cur[NSH];
    const int tid = threadIdx.x;   // 512 threads == NSH
    h[tid] = 0;
    __syncthreads();
    for (int i = tid; i < NB; i += 512) atomicAdd(&h[shard[i]], 1);
    __syncthreads();
    if (tid == 0) {
        int acc = 0;
        for (int s = 0; s < NSH; ++s) { b0[s] = acc; acc += h[s]; }
    }
    __syncthreads();
    cnt[tid]  = h[tid];
    base[tid] = b0[tid];
    cur[tid]  = b0[tid];
    __syncthreads();
    for (int i = tid; i < NB; i += 512) {
        int pos = atomicAdd(&cur[shard[i]], 1);
        order[pos] = i;
    }
}

// ---------------- Kernel 2: partial logits, one block per (shard, i-chunk) --
// partial[ic][b][c] = sum_{i in chunk} key[b][i] * W[s][i][c]
__global__ __launch_bounds__(256) void logit_kernel(
        const int*   __restrict__ order,
        const int*   __restrict__ base,
        const int*   __restrict__ cnt,
        const float* __restrict__ key,
        const float* __restrict__ wgt,
        float*       __restrict__ partial) {
    const int s  = blockIdx.x >> 2;
    const int ic = blockIdx.x & 3;
    const int n_tot = cnt[s];
    if (n_tot == 0) return;
    const int b0  = base[s];
    const int tid = threadIdx.x;
    const int w   = tid >> 6;             // i-phase (wave)
    const int c4  = (tid & 63) << 2;      // 4 clusters per lane

    const float* __restrict__ Wp = wgt + (size_t)s * (NI * NC) + (size_t)(ic * 256) * NC;

    __shared__ float key_s[NMAX][256];    // 8 KB
    __shared__ float red_s[4][2][NC];     // 8 KB
    __shared__ int   samp_s[NMAX];

    for (int p0 = 0; p0 < n_tot; p0 += NMAX) {
        const int n = min(NMAX, n_tot - p0);
        __syncthreads();
        if (tid < n) samp_s[tid] = order[b0 + p0 + tid];
        __syncthreads();

        // stage key chunk: 8 samples x 256 floats (zero-padded)
        for (int idx = tid; idx < NMAX * 64; idx += 256) {
            const int ns = idx >> 6;
            const int e4 = idx & 63;
            float4 v = make_float4(0.f, 0.f, 0.f, 0.f);
            if (ns < n)
                v = *(const float4*)(key + (size_t)samp_s[ns] * NI + ic * 256 + (e4 << 2));
            *(float4*)&key_s[ns][e4 << 2] = v;
        }
        __syncthreads();

        float4 acc[NMAX];
        #pragma unroll
        for (int j = 0; j < NMAX; ++j) acc[j] = make_float4(0.f, 0.f, 0.f, 0.f);

        for (int k0 = 0; k0 < 64; k0 += UF) {
            float4 wv[UF];
            #pragma unroll
            for (int u = 0; u < UF; ++u)
                wv[u] = *(const float4*)(Wp + (size_t)(w + 4 * (k0 + u)) * NC + c4);
            #pragma unroll
            for (int u = 0; u < UF; ++u) {
                const int il = w + 4 * (k0 + u);
                #pragma unroll
                for (int j = 0; j < NMAX; ++j) {
                    const float k = key_s[j][il];
                    acc[j].x = fmaf(k, wv[u].x, acc[j].x);
                    acc[j].y = fmaf(k, wv[u].y, acc[j].y);
                    acc[j].z = fmaf(k, wv[u].z, acc[j].z);
                    acc[j].w = fmaf(k, wv[u].w, acc[j].w);
                }
            }
        }

        // cross-wave reduce, 2 samples per round
        #pragma unroll
        for (int r = 0; r < 4; ++r) {
            __syncthreads();
            *(float4*)&red_s[w][0][c4] = acc[2 * r];
            *(float4*)&red_s[w][1][c4] = acc[2 * r + 1];
            __syncthreads();
            const float s0 = red_s[0][0][tid] + red_s[1][0][tid]
                           + red_s[2][0][tid] + red_s[3][0][tid];
            const float s1 = red_s[0][1][tid] + red_s[1][1][tid]
                           + red_s[2][1][tid] + red_s[3][1][tid];
            if (2 * r < n)
                partial[((size_t)ic * NB + samp_s[2 * r]) * NC + tid] = s0;
            if (2 * r + 1 < n)
                partial[((size_t)ic * NB + samp_s[2 * r + 1]) * NC + tid] = s1;
        }
    }
}

// ---------------- Kernel 3: reduce partials + bias, softmax, write prob -----
__global__ __launch_bounds__(256) void softmax_kernel(
        const int*   __restrict__ shard,
        const float* __restrict__ bias,
        const float* __restrict__ partial,
        float*       __restrict__ outq) {
    const int b    = blockIdx.x;
    const int tid  = threadIdx.x;
    const int wv   = tid >> 6;
    const int lane = tid & 63;

    float lg = bias[(size_t)shard[b] * NC + tid];
    #pragma unroll
    for (int ic = 0; ic < IC; ++ic)
        lg += partial[((size_t)ic * NB + b) * NC + tid];

    __shared__ float xw[4];
    float m = lg;
    #pragma unroll
    for (int off = 32; off >= 1; off >>= 1)
        m = fmaxf(m, __shfl_xor(m, off, 64));
    if (lane == 0) xw[wv] = m;
    __syncthreads();
    m = fmaxf(fmaxf(xw[0], xw[1]), fmaxf(xw[2], xw[3]));
    const float e = __expf(lg - m);
    float sm = e;
    #pragma unroll
    for (int off = 32; off >= 1; off >>= 1)
        sm += __shfl_xor(sm, off, 64);
    __syncthreads();
    if (lane == 0) xw[wv] = sm;
    __syncthreads();
    sm = xw[0] + xw[1] + xw[2] + xw[3];
    outq[(size_t)b * NC + tid] = e / sm;
}

// ---------------- Kernel 4: combine, one block per (shard, o-chunk) ---------
// lat_h[b][o] = sum_c prob[b][c] * L[s][c][o]
__global__ __launch_bounds__(256) void combine_kernel(
        const int*   __restrict__ order,
        const int*   __restrict__ base,
        const int*   __restrict__ cnt,
        const float* __restrict__ prob,
        const float* __restrict__ lat,
        float*       __restrict__ outp) {
    const int s  = blockIdx.x >> 2;
    const int oc = blockIdx.x & 3;
    const int n_tot = cnt[s];
    if (n_tot == 0) return;
    const int b0  = base[s];
    const int tid = threadIdx.x;
    const int w   = tid >> 6;             // c-phase (wave)
    const int o4  = (tid & 63) << 2;      // 4 outputs per lane within chunk

    const float* __restrict__ Lp = lat + (size_t)s * (NC * NO) + oc * 256;

    __shared__ float prob_s[NMAX][NC];    // 8 KB
    __shared__ float red_s[4][2][256];    // 8 KB
    __shared__ int   samp_s[NMAX];

    for (int p0 = 0; p0 < n_tot; p0 += NMAX) {
        const int n = min(NMAX, n_tot - p0);
        __syncthreads();
        if (tid < n) samp_s[tid] = order[b0 + p0 + tid];
        __syncthreads();

        // stage prob: 8 samples x 256 floats (zero-padded)
        for (int idx = tid; idx < NMAX * 64; idx += 256) {
            const int ns = idx >> 6;
            const int e4 = idx & 63;
            float4 v = make_float4(0.f, 0.f, 0.f, 0.f);
            if (ns < n)
                v = *(const float4*)(prob + (size_t)samp_s[ns] * NC + (e4 << 2));
            *(float4*)&prob_s[ns][e4 << 2] = v;
        }
        __syncthreads();

        float4 acc[NMAX];
        #pragma unroll
        for (int j = 0; j < NMAX; ++j) acc[j] = make_float4(0.f, 0.f, 0.f, 0.f);

        for (int k0 = 0; k0 < 64; k0 += UF) {
            float4 lv[UF];
            #pragma unroll
            for (int u = 0; u < UF; ++u)
                lv[u] = *(const float4*)(Lp + (size_t)(w + 4 * (k0 + u)) * NO + o4);
            #pragma unroll
            for (int u = 0; u < UF; ++u) {
                const int c = w + 4 * (k0 + u);
                #pragma unroll
                for (int j = 0; j < NMAX; ++j) {
                    const float p = prob_s[j][c];
                    acc[j].x = fmaf(p, lv[u].x, acc[j].x);
                    acc[j].y = fmaf(p, lv[u].y, acc[j].y);
                    acc[j].z = fmaf(p, lv[u].z, acc[j].z);
                    acc[j].w = fmaf(p, lv[u].w, acc[j].w);
                }
            }
        }

        // cross-wave reduce over c-phases, 2 samples per round
        #pragma unroll
        for (int r = 0; r < 4; ++r) {
            __syncthreads();
            *(float4*)&red_s[w][0][o4] = acc[2 * r];
            *(float4*)&red_s[w][1][o4] = acc[2 * r + 1];
            __syncthreads();
            const float s0 = red_s[0][0][tid] + red_s[1][0][tid]
                           + red_s[2][0][tid] + red_s[3][0][tid];
            const float s1 = red_s[0][1][tid] + red_s[1][1][tid]
                           + red_s[2][1][tid] + red_s[3][1][tid];
            if (2 * r < n)
                outp[(size_t)samp_s[2 * r] * NO + oc * 256 + tid] = s0;
            if (2 * r + 1 < n)
                outp[(size_t)samp_s[2 * r + 1] * NO + oc * 256 + tid] = s1;
        }
    }
}

// ---------------- launch ----------------------------------------------------
extern "C" void kernel_launch(void* const* d_in, const int* in_sizes, int n_in,
                              void* d_out, int out_size, void* d_ws, size_t ws_size,
                              hipStream_t stream) {
    const int*   shard = (const int*)  d_in[0];
    const float* key   = (const float*)d_in[1];
    const float* lat   = (const float*)d_in[2];
    const float* wgt   = (const float*)d_in[3];
    const float* bias  = (const float*)d_in[4];

    float* outp = (float*)d_out;                       // lat_h [NB][NO]
    float* outq = (float*)d_out + (size_t)NB * NO;     // prob  [NB][NC]

    int*   order   = (int*)d_ws;           // [NB]
    int*   base    = order + NB;           // [NSH]
    int*   cnt     = base + NSH;           // [NSH]
    float* partial = (float*)(cnt + NSH);  // [IC][NB][NC] = 4 MB

    group_kernel  <<<1,        512, 0, stream>>>(shard, order, base, cnt);
    logit_kernel  <<<NSH * IC, 256, 0, stream>>>(order, base, cnt, key, wgt, partial);
    softmax_kernel<<<NB,       256, 0, stream>>>(shard, bias, partial, outq);
    combine_kernel<<<NSH * OC, 256, 0, stream>>>(order, base, cnt, outq, lat, outp);
}